// Round 3
// baseline (4189.092 us; speedup 1.0000x reference)
//
#include <hip/hip_runtime.h>
#include <cstddef>

#define BB 64
#define PP 196
#define ENCD 2048
#define DECD 512
#define ATTD 512
#define EMBD 512
#define VOC 9490
#define NFC2 9600  // VOC padded to 128-col tiles
#define TDEC 20
#define F2STR 2560  // F2 row: [att2 512 | gate 2048]

using u16 = unsigned short;
using short8 = __attribute__((ext_vector_type(8))) short;   // 8 bf16 (4 VGPRs)
using f32x16 = __attribute__((ext_vector_type(16))) float;  // 32x32 acc

__device__ __forceinline__ float sigmoidf_(float x) { return 1.f / (1.f + __expf(-x)); }

// ---- fp32 -> bf16 RNE, and hi/lo split (x ~= hi + lo, err ~2^-17 |x|) -----
__device__ __forceinline__ unsigned rne_bf(float x) {
  unsigned u = __float_as_uint(x);
  return (u + 0x7FFFu + ((u >> 16) & 1u)) >> 16;
}
__device__ __forceinline__ void split_bf(float x, u16& h, u16& l) {
  unsigned hu = rne_bf(x);
  h = (u16)hu;
  float hf = __uint_as_float(hu << 16);
  l = (u16)rne_bf(x - hf);
}
__device__ __forceinline__ uint4 pack8(const u16* s) {
  uint4 r;
  r.x = (unsigned)s[0] | ((unsigned)s[1] << 16);
  r.y = (unsigned)s[2] | ((unsigned)s[3] << 16);
  r.z = (unsigned)s[4] | ((unsigned)s[5] << 16);
  r.w = (unsigned)s[6] | ((unsigned)s[7] << 16);
  return r;
}

// Swizzled elem offset into a [rows][64] u16 LDS tile: row stride 128B = 8 x
// 16B blocks; block index XOR row&7 -> banked-floor b128 write AND read.
#define LADDRE(row, bk) (((row) << 6) + ((((bk) ^ ((row)&7))) << 3))

#define MFMA_TRIPLE(ACC, AH, AL, BH, BL)                                      \
  ACC = __builtin_amdgcn_mfma_f32_32x32x16_bf16(AH, BH, ACC, 0, 0, 0);        \
  ACC = __builtin_amdgcn_mfma_f32_32x32x16_bf16(AH, BL, ACC, 0, 0, 0);        \
  ACC = __builtin_amdgcn_mfma_f32_32x32x16_bf16(AL, BH, ACC, 0, 0, 0);

// C/D layout (verified r1): col = lane&31, row = (g&3) + 8*(g>>2) + 4*(lane>>5)
#define OROW(ri, g, lh) ((ri)*32 + ((g)&3) + 8 * ((g) >> 2) + 4 * (lh))

// ---- one-time: W[k][n] (k<K, row-stride ld) fp32 -> Th/Tl [Npad64][K] ------
__global__ __launch_bounds__(256) void convT_kernel(const float* __restrict__ W,
                                                    int ld, int K, int N,
                                                    u16* __restrict__ Th,
                                                    u16* __restrict__ Tl) {
  __shared__ u16 ht[64][66], lt[64][66];
  int t = threadIdx.x;
  int k0 = blockIdx.x * 64, n0 = blockIdx.y * 64;
  int nl = t & 63, kq = t >> 6;
  int n = n0 + nl;
#pragma unroll
  for (int i = 0; i < 16; ++i) {
    int k = kq * 16 + i;
    float v = (n < N) ? W[(size_t)(k0 + k) * ld + n] : 0.f;
    u16 h, l;
    split_bf(v, h, l);
    ht[k][nl] = h;
    lt[k][nl] = l;
  }
  __syncthreads();
  int n2 = t >> 2, q = t & 3;
  u16 h16[16], l16[16];
#pragma unroll
  for (int i = 0; i < 16; ++i) {
    h16[i] = ht[q * 16 + i][n2];
    l16[i] = lt[q * 16 + i][n2];
  }
  size_t ob = (size_t)(n0 + n2) * K + k0 + q * 16;
  *(uint4*)(Th + ob) = pack8(h16);
  *(uint4*)(Th + ob + 8) = pack8(h16 + 8);
  *(uint4*)(Tl + ob) = pack8(l16);
  *(uint4*)(Tl + ob + 8) = pack8(l16 + 8);
}

// ---- split-bf16 MFMA core: C[64 x 128] = A(f32) @ BT(split) ---------------
// a_s: this thread's A source (row t&63, k-chunk (t>>6)*16), contiguous in k.
// bh_s/bl_s: this thread's B source (row tile + (t&127), u16 ofs (t>>7)*32).
// 4 waves; wave w owns cols [w*32, w*32+32); acc[ri] covers rows ri*32..+32.
__device__ __forceinline__ void core32(const float* a_s, const u16* bh_s,
                                       const u16* bl_s, int k0s, int k0e,
                                       u16* Ah, u16* Al, u16* Bh, u16* Bl,
                                       f32x16 (&acc)[2]) {
  int t = threadIdx.x;
  int ar = t & 63, akc = t >> 6;
  int br = t & 127, bb = (t >> 7) * 4;
  int l31 = t & 31, lh = (t >> 5) & 1, w = t >> 6;
  for (int k0 = k0s; k0 < k0e; k0 += 64) {
    float av[16];
    *(float4*)(av + 0) = *(const float4*)(a_s + k0);
    *(float4*)(av + 4) = *(const float4*)(a_s + k0 + 4);
    *(float4*)(av + 8) = *(const float4*)(a_s + k0 + 8);
    *(float4*)(av + 12) = *(const float4*)(a_s + k0 + 12);
    uint4 bhv[4], blv[4];
#pragma unroll
    for (int j = 0; j < 4; ++j) {
      bhv[j] = *(const uint4*)(bh_s + k0 + j * 8);
      blv[j] = *(const uint4*)(bl_s + k0 + j * 8);
    }
    u16 h[16], l[16];
#pragma unroll
    for (int i = 0; i < 16; ++i) split_bf(av[i], h[i], l[i]);
    __syncthreads();  // previous iteration's fragment reads done
    *(uint4*)(Ah + LADDRE(ar, akc * 2)) = pack8(h);
    *(uint4*)(Ah + LADDRE(ar, akc * 2 + 1)) = pack8(h + 8);
    *(uint4*)(Al + LADDRE(ar, akc * 2)) = pack8(l);
    *(uint4*)(Al + LADDRE(ar, akc * 2 + 1)) = pack8(l + 8);
#pragma unroll
    for (int j = 0; j < 4; ++j) {
      *(uint4*)(Bh + LADDRE(br, bb + j)) = bhv[j];
      *(uint4*)(Bl + LADDRE(br, bb + j)) = blv[j];
    }
    __syncthreads();
#pragma unroll
    for (int ks = 0; ks < 4; ++ks) {
      int bk = ks * 2 + lh;
      short8 a0h = *(const short8*)(Ah + LADDRE(l31, bk));
      short8 a1h = *(const short8*)(Ah + LADDRE(32 + l31, bk));
      short8 a0l = *(const short8*)(Al + LADDRE(l31, bk));
      short8 a1l = *(const short8*)(Al + LADDRE(32 + l31, bk));
      int brw = w * 32 + l31;
      short8 bh = *(const short8*)(Bh + LADDRE(brw, bk));
      short8 bl = *(const short8*)(Bl + LADDRE(brw, bk));
      MFMA_TRIPLE(acc[0], a0h, a0l, bh, bl);
      MFMA_TRIPLE(acc[1], a1h, a1l, bh, bl);
    }
  }
}

// ---- att1 = enc(b,k,p)^T @ W_enc_att + bias; 64r x 256c, two-phase B ------
__global__ __launch_bounds__(256) void att1_mfma(const float* __restrict__ enc,
                                                 const u16* __restrict__ BTh,
                                                 const u16* __restrict__ BTl,
                                                 const float* __restrict__ bea,
                                                 float* __restrict__ att1) {
  __shared__ u16 Ah[4096], Al[4096], Bh[8192], Bl[8192];
  int t = threadIdx.x;
  int n0 = blockIdx.x * 256;      // grid.x = 2
  int rowbase = blockIdx.y * 64;  // grid.y = 196
  int ar = t & 63, akc = t >> 6;
  int r = rowbase + ar;
  int ab = r / PP, ap = r - ab * PP;
  const float* asrc = enc + (size_t)ab * (ENCD * PP) + ap;
  int br = t & 127, bb = (t >> 7) * 4;
  const u16* bh_s0 = BTh + (size_t)(n0 + br) * ENCD + bb * 8;
  const u16* bl_s0 = BTl + (size_t)(n0 + br) * ENCD + bb * 8;
  const u16* bh_s1 = bh_s0 + (size_t)128 * ENCD;
  const u16* bl_s1 = bl_s0 + (size_t)128 * ENCD;
  int l31 = t & 31, lh = (t >> 5) & 1, w = t >> 6;
  f32x16 acc[2][2];  // [row-half][col-phase]
#pragma unroll
  for (int a = 0; a < 2; ++a)
#pragma unroll
    for (int b = 0; b < 2; ++b)
#pragma unroll
      for (int i = 0; i < 16; ++i) acc[a][b][i] = 0.f;

  for (int k0 = 0; k0 < ENCD; k0 += 64) {
    float av[16];
#pragma unroll
    for (int i = 0; i < 16; ++i) av[i] = asrc[(size_t)(k0 + akc * 16 + i) * PP];
    uint4 b0h[4], b0l[4];
#pragma unroll
    for (int j = 0; j < 4; ++j) {
      b0h[j] = *(const uint4*)(bh_s0 + k0 + j * 8);
      b0l[j] = *(const uint4*)(bl_s0 + k0 + j * 8);
    }
    u16 h[16], l[16];
#pragma unroll
    for (int i = 0; i < 16; ++i) split_bf(av[i], h[i], l[i]);
    __syncthreads();  // phase-1 reads of previous iteration done
    *(uint4*)(Ah + LADDRE(ar, akc * 2)) = pack8(h);
    *(uint4*)(Ah + LADDRE(ar, akc * 2 + 1)) = pack8(h + 8);
    *(uint4*)(Al + LADDRE(ar, akc * 2)) = pack8(l);
    *(uint4*)(Al + LADDRE(ar, akc * 2 + 1)) = pack8(l + 8);
#pragma unroll
    for (int j = 0; j < 4; ++j) {
      *(uint4*)(Bh + LADDRE(br, bb + j)) = b0h[j];
      *(uint4*)(Bl + LADDRE(br, bb + j)) = b0l[j];
    }
    __syncthreads();
    uint4 b1h[4], b1l[4];  // prefetch phase-1 B while computing phase 0
#pragma unroll
    for (int j = 0; j < 4; ++j) {
      b1h[j] = *(const uint4*)(bh_s1 + k0 + j * 8);
      b1l[j] = *(const uint4*)(bl_s1 + k0 + j * 8);
    }
#pragma unroll
    for (int ks = 0; ks < 4; ++ks) {
      int bk = ks * 2 + lh;
      short8 a0h = *(const short8*)(Ah + LADDRE(l31, bk));
      short8 a1h = *(const short8*)(Ah + LADDRE(32 + l31, bk));
      short8 a0l = *(const short8*)(Al + LADDRE(l31, bk));
      short8 a1l = *(const short8*)(Al + LADDRE(32 + l31, bk));
      int brw = w * 32 + l31;
      short8 bh = *(const short8*)(Bh + LADDRE(brw, bk));
      short8 bl = *(const short8*)(Bl + LADDRE(brw, bk));
      MFMA_TRIPLE(acc[0][0], a0h, a0l, bh, bl);
      MFMA_TRIPLE(acc[1][0], a1h, a1l, bh, bl);
    }
    __syncthreads();  // phase-0 B reads done
#pragma unroll
    for (int j = 0; j < 4; ++j) {
      *(uint4*)(Bh + LADDRE(br, bb + j)) = b1h[j];
      *(uint4*)(Bl + LADDRE(br, bb + j)) = b1l[j];
    }
    __syncthreads();
#pragma unroll
    for (int ks = 0; ks < 4; ++ks) {
      int bk = ks * 2 + lh;
      short8 a0h = *(const short8*)(Ah + LADDRE(l31, bk));
      short8 a1h = *(const short8*)(Ah + LADDRE(32 + l31, bk));
      short8 a0l = *(const short8*)(Al + LADDRE(l31, bk));
      short8 a1l = *(const short8*)(Al + LADDRE(32 + l31, bk));
      int brw = w * 32 + l31;
      short8 bh = *(const short8*)(Bh + LADDRE(brw, bk));
      short8 bl = *(const short8*)(Bl + LADDRE(brw, bk));
      MFMA_TRIPLE(acc[0][1], a0h, a0l, bh, bl);
      MFMA_TRIPLE(acc[1][1], a1h, a1l, bh, bl);
    }
  }
#pragma unroll
  for (int ri = 0; ri < 2; ++ri)
#pragma unroll
    for (int ph = 0; ph < 2; ++ph) {
      int col = n0 + ph * 128 + w * 32 + l31;
      float bv = bea[col];
#pragma unroll
      for (int g = 0; g < 16; ++g) {
        int row = rowbase + OROW(ri, g, lh);
        att1[(size_t)row * ATTD + col] = acc[ri][ph][g] + bv;
      }
    }
}

// ---- gates0[t*64+b][n] = emb(tok) @ W_ih_top + b_ih + b_hh (fused gather) --
__global__ __launch_bounds__(256) void embgates_mfma(
    const int* __restrict__ captions, const float* __restrict__ embedding,
    const u16* __restrict__ Bh_g, const u16* __restrict__ Bl_g,
    const float* __restrict__ b1, const float* __restrict__ b2,
    float* __restrict__ gates0) {
  __shared__ u16 Ah[4096], Al[4096], Bh[8192], Bl[8192];
  int t = threadIdx.x;
  int n0 = blockIdx.x * 128;       // grid (16, 20)
  int tt = blockIdx.y;
  int ar = t & 63;
  int tok = captions[ar * 21 + tt];
  const float* a_s = embedding + (size_t)tok * EMBD + (t >> 6) * 16;
  int br = t & 127;
  const u16* bh_s = Bh_g + (size_t)(n0 + br) * DECD + (t >> 7) * 32;
  const u16* bl_s = Bl_g + (size_t)(n0 + br) * DECD + (t >> 7) * 32;
  f32x16 acc[2];
#pragma unroll
  for (int a = 0; a < 2; ++a)
#pragma unroll
    for (int i = 0; i < 16; ++i) acc[a][i] = 0.f;
  core32(a_s, bh_s, bl_s, 0, DECD, Ah, Al, Bh, Bl, acc);
  int l31 = t & 31, lh = (t >> 5) & 1, w = t >> 6;
  int col = n0 + w * 32 + l31;
  float bv = b1[col] + b2[col];
#pragma unroll
  for (int ri = 0; ri < 2; ++ri)
#pragma unroll
    for (int g = 0; g < 16; ++g) {
      int row = tt * 64 + OROW(ri, g, lh);
      gates0[(size_t)row * 2048 + col] = acc[ri][g] + bv;
    }
}

// ---- per-step: h @ [Wdec | Wfbeta(sigmoid) | Whh(+gates0)] ----------------
__global__ __launch_bounds__(256) void hgemm_mfma(
    const float* __restrict__ hprev, const u16* __restrict__ Bh_g,
    const u16* __restrict__ Bl_g, const float* __restrict__ bdec,
    const float* __restrict__ bfb, const float* __restrict__ g0,
    float* __restrict__ F2, float* __restrict__ gates) {
  __shared__ u16 Ah[4096], Al[4096], Bh[8192], Bl[8192];
  int t = threadIdx.x;
  int n0 = blockIdx.x * 128;  // grid 36
  const float* a_s = hprev + (size_t)(t & 63) * DECD + (t >> 6) * 16;
  int br = t & 127;
  const u16* bh_s = Bh_g + (size_t)(n0 + br) * DECD + (t >> 7) * 32;
  const u16* bl_s = Bl_g + (size_t)(n0 + br) * DECD + (t >> 7) * 32;
  f32x16 acc[2];
#pragma unroll
  for (int a = 0; a < 2; ++a)
#pragma unroll
    for (int i = 0; i < 16; ++i) acc[a][i] = 0.f;
  core32(a_s, bh_s, bl_s, 0, DECD, Ah, Al, Bh, Bl, acc);
  int l31 = t & 31, lh = (t >> 5) & 1, w = t >> 6;
  int col = n0 + w * 32 + l31;
#pragma unroll
  for (int ri = 0; ri < 2; ++ri)
#pragma unroll
    for (int g = 0; g < 16; ++g) {
      int b = OROW(ri, g, lh);
      float v = acc[ri][g];
      if (n0 < ATTD) {
        F2[(size_t)b * F2STR + col] = v + bdec[col];
      } else if (n0 < ATTD + ENCD) {
        F2[(size_t)b * F2STR + col] = sigmoidf_(v + bfb[col - ATTD]);
      } else {
        int cg = col - (ATTD + ENCD);
        gates[(size_t)b * 2048 + cg] = v + g0[(size_t)b * 2048 + cg];
      }
    }
}

// ---- per-step: gates += awe @ W_ih_bot (K=2048, 2-way k-split atomic) ------
__global__ __launch_bounds__(256) void gates_mfma(const float* __restrict__ awe,
                                                  const u16* __restrict__ Bh_g,
                                                  const u16* __restrict__ Bl_g,
                                                  float* __restrict__ gates) {
  __shared__ u16 Ah[4096], Al[4096], Bh[8192], Bl[8192];
  int t = threadIdx.x;
  int n0 = blockIdx.x * 128;  // grid (16, 2)
  int k0s = blockIdx.y * 1024;
  const float* a_s = awe + (size_t)(t & 63) * ENCD + (t >> 6) * 16;
  int br = t & 127;
  const u16* bh_s = Bh_g + (size_t)(n0 + br) * ENCD + (t >> 7) * 32;
  const u16* bl_s = Bl_g + (size_t)(n0 + br) * ENCD + (t >> 7) * 32;
  f32x16 acc[2];
#pragma unroll
  for (int a = 0; a < 2; ++a)
#pragma unroll
    for (int i = 0; i < 16; ++i) acc[a][i] = 0.f;
  core32(a_s, bh_s, bl_s, k0s, k0s + 1024, Ah, Al, Bh, Bl, acc);
  int l31 = t & 31, lh = (t >> 5) & 1, w = t >> 6;
  int col = n0 + w * 32 + l31;
#pragma unroll
  for (int ri = 0; ri < 2; ++ri)
#pragma unroll
    for (int g = 0; g < 16; ++g) {
      int b = OROW(ri, g, lh);
      atomicAdd(&gates[(size_t)b * 2048 + col], acc[ri][g]);
    }
}

// ---- preds = Hfc(1280x512) @ W_fc + b_fc ----------------------------------
__global__ __launch_bounds__(256) void fc_mfma(const float* __restrict__ Hfc,
                                               const u16* __restrict__ Bh_g,
                                               const u16* __restrict__ Bl_g,
                                               const float* __restrict__ bfc,
                                               float* __restrict__ preds) {
  __shared__ u16 Ah[4096], Al[4096], Bh[8192], Bl[8192];
  int t = threadIdx.x;
  int n0 = blockIdx.x * 128;      // grid (75, 20)
  int rowbase = blockIdx.y * 64;
  const float* a_s = Hfc + (size_t)(rowbase + (t & 63)) * DECD + (t >> 6) * 16;
  int br = t & 127;
  const u16* bh_s = Bh_g + (size_t)(n0 + br) * DECD + (t >> 7) * 32;
  const u16* bl_s = Bl_g + (size_t)(n0 + br) * DECD + (t >> 7) * 32;
  f32x16 acc[2];
#pragma unroll
  for (int a = 0; a < 2; ++a)
#pragma unroll
    for (int i = 0; i < 16; ++i) acc[a][i] = 0.f;
  core32(a_s, bh_s, bl_s, 0, DECD, Ah, Al, Bh, Bl, acc);
  int l31 = t & 31, lh = (t >> 5) & 1, w = t >> 6;
  int col = n0 + w * 32 + l31;
  if (col < VOC) {
    float bv = bfc[col];
#pragma unroll
    for (int ri = 0; ri < 2; ++ri)
#pragma unroll
      for (int g = 0; g < 16; ++g) {
        int rr = rowbase + OROW(ri, g, lh);
        preds[(size_t)(rr & 63) * (TDEC * VOC) + (size_t)(rr >> 6) * VOC + col] =
            acc[ri][g] + bv;
      }
  }
}

// ---------------- mean over P of encoder_out rows (B*ENC rows of 196) -------
__global__ __launch_bounds__(256) void mean_kernel(const float* __restrict__ enc,
                                                   float* __restrict__ mean) {
  int row = blockIdx.x * 4 + (threadIdx.x >> 6);
  int lane = threadIdx.x & 63;
  const float* r = enc + (size_t)row * PP;
  float v = r[lane] + r[lane + 64] + r[lane + 128];
  if (lane < 4) v += r[lane + 192];
#pragma unroll
  for (int off = 32; off; off >>= 1) v += __shfl_down(v, off);
  if (lane == 0) mean[row] = v * (1.f / 196.f);
}

// ---------------- 64-row x 64-col GEMM, k-split atomic (init h0/c0) ---------
__global__ __launch_bounds__(256) void gemm64_atomic(
    const float* __restrict__ A, int lda, const float* __restrict__ W, int ldw,
    float* __restrict__ C, int ldc, const float* __restrict__ bias0, int kchunk) {
  __shared__ __align__(16) float As[16][68];
  int tid = threadIdx.x;
  int my = tid >> 4, nx = tid & 15;
  int am = tid >> 2, ak = (tid & 3) << 2;
  int n0 = blockIdx.x * 64;
  int k0s = blockIdx.y * kchunk, k0e = k0s + kchunk;
  float acc[4][4] = {};
  for (int k0 = k0s; k0 < k0e; k0 += 16) {
    float4 a4 = *(const float4*)(A + (size_t)am * lda + k0 + ak);
    As[ak + 0][am] = a4.x;
    As[ak + 1][am] = a4.y;
    As[ak + 2][am] = a4.z;
    As[ak + 3][am] = a4.w;
    __syncthreads();
    const float* wp = W + (size_t)k0 * ldw + n0 + (nx << 2);
#pragma unroll
    for (int kk = 0; kk < 16; ++kk) {
      float4 av = *(const float4*)&As[kk][my << 2];
      float4 wv = *(const float4*)(wp + (size_t)kk * ldw);
      acc[0][0] = fmaf(av.x, wv.x, acc[0][0]); acc[0][1] = fmaf(av.x, wv.y, acc[0][1]);
      acc[0][2] = fmaf(av.x, wv.z, acc[0][2]); acc[0][3] = fmaf(av.x, wv.w, acc[0][3]);
      acc[1][0] = fmaf(av.y, wv.x, acc[1][0]); acc[1][1] = fmaf(av.y, wv.y, acc[1][1]);
      acc[1][2] = fmaf(av.y, wv.z, acc[1][2]); acc[1][3] = fmaf(av.y, wv.w, acc[1][3]);
      acc[2][0] = fmaf(av.z, wv.x, acc[2][0]); acc[2][1] = fmaf(av.z, wv.y, acc[2][1]);
      acc[2][2] = fmaf(av.z, wv.z, acc[2][2]); acc[2][3] = fmaf(av.z, wv.w, acc[2][3]);
      acc[3][0] = fmaf(av.w, wv.x, acc[3][0]); acc[3][1] = fmaf(av.w, wv.y, acc[3][1]);
      acc[3][2] = fmaf(av.w, wv.z, acc[3][2]); acc[3][3] = fmaf(av.w, wv.w, acc[3][3]);
    }
    __syncthreads();
  }
  bool first = (blockIdx.y == 0);
#pragma unroll
  for (int i = 0; i < 4; ++i) {
    int row = (my << 2) + i;
#pragma unroll
    for (int j = 0; j < 4; ++j) {
      int col = n0 + (nx << 2) + j;
      float v = acc[i][j];
      if (first && bias0) v += bias0[col];
      atomicAdd(&C[(size_t)row * ldc + col], v);
    }
  }
}

// -------- score[b,p] = sum_a relu(att1+att2)*wf : one wave per (b,p) --------
__global__ __launch_bounds__(256) void score_kernel(const float* __restrict__ att1,
                                                    const float* __restrict__ F2,
                                                    const float* __restrict__ W_full,
                                                    float* __restrict__ scores) {
  int w = blockIdx.x * 4 + (threadIdx.x >> 6);  // [0, 12544)
  int lane = threadIdx.x & 63;
  int b = w / PP, p = w - b * PP;
  const float4* row = (const float4*)(att1 + ((size_t)b * PP + p) * ATTD) + (lane << 1);
  const float4* a2 = (const float4*)(F2 + (size_t)b * F2STR) + (lane << 1);
  const float4* w4 = (const float4*)W_full + (lane << 1);
  float acc = 0.f;
#pragma unroll
  for (int i = 0; i < 2; ++i) {
    float4 v = row[i], a = a2[i], wf = w4[i];
    acc = fmaf(fmaxf(v.x + a.x, 0.f), wf.x, acc);
    acc = fmaf(fmaxf(v.y + a.y, 0.f), wf.y, acc);
    acc = fmaf(fmaxf(v.z + a.z, 0.f), wf.z, acc);
    acc = fmaf(fmaxf(v.w + a.w, 0.f), wf.w, acc);
  }
#pragma unroll
  for (int off = 32; off; off >>= 1) acc += __shfl_down(acc, off);
  if (lane == 0) scores[b * PP + p] = acc;
}

// -------- softmax(196) per block + gated awe for a 256-wide e-slice ---------
__global__ __launch_bounds__(256) void awe_softmax_kernel(
    const float* __restrict__ scores, const float* __restrict__ F2,
    const float* __restrict__ enc, float* __restrict__ alphas_out,
    float* __restrict__ awe, int t) {
  int b = blockIdx.y, et = blockIdx.x, tid = threadIdx.x;
  __shared__ __align__(16) float al[256];
  __shared__ float sc[256];
  __shared__ float red[256];
  float s = (tid < PP) ? scores[b * PP + tid] : -1e30f;
  sc[tid] = s;
  __syncthreads();
  for (int off = 128; off; off >>= 1) {
    if (tid < off) sc[tid] = fmaxf(sc[tid], sc[tid + off]);
    __syncthreads();
  }
  float e = (tid < PP) ? __expf(s - sc[0]) : 0.f;
  red[tid] = e;
  __syncthreads();
  for (int off = 128; off; off >>= 1) {
    if (tid < off) red[tid] += red[tid + off];
    __syncthreads();
  }
  float a = e * (1.f / red[0]);
  al[tid] = a;
  if (et == 0 && tid < PP)
    alphas_out[(size_t)b * (TDEC * PP) + (size_t)t * PP + tid] = a;
  __syncthreads();
  int e0 = et * 256 + tid;
  const float4* row = (const float4*)(enc + ((size_t)b * ENCD + e0) * PP);
  const float4* al4 = (const float4*)al;
  float acc = 0.f;
#pragma unroll 7
  for (int i = 0; i < PP / 4; ++i) {
    float4 v = row[i], aa = al4[i];
    acc = fmaf(v.x, aa.x, acc);
    acc = fmaf(v.y, aa.y, acc);
    acc = fmaf(v.z, aa.z, acc);
    acc = fmaf(v.w, aa.w, acc);
  }
  float gate = F2[(size_t)b * F2STR + ATTD + e0];
  awe[(size_t)b * ENCD + e0] = gate * acc;
}

// ---- LSTM pointwise -> h into Hbuf slot ------------------------------------
__global__ __launch_bounds__(256) void lstm_kernel(const float* __restrict__ gates,
                                                   float* __restrict__ c,
                                                   float* __restrict__ hout) {
  int idx = blockIdx.x * 256 + threadIdx.x;  // 0..32767
  int b = idx >> 9, d = idx & 511;
  const float* g = gates + (size_t)b * 2048;
  float gi = g[d], gf = g[d + 512], gg = g[d + 1024], go = g[d + 1536];
  float iv = sigmoidf_(gi);
  float fv = sigmoidf_(gf);
  float ov = sigmoidf_(go);
  float gv = tanhf(gg);
  float cn = fv * c[idx] + iv * gv;
  c[idx] = cn;
  hout[idx] = ov * tanhf(cn);
}

extern "C" void kernel_launch(void* const* d_in, const int* in_sizes, int n_in,
                              void* d_out, int out_size, void* d_ws, size_t ws_size,
                              hipStream_t stream) {
  const float* enc = (const float*)d_in[0];
  const int* captions = (const int*)d_in[1];
  const float* W_enc_att = (const float*)d_in[2];
  const float* b_enc_att = (const float*)d_in[3];
  const float* W_dec_att = (const float*)d_in[4];
  const float* b_dec_att = (const float*)d_in[5];
  const float* W_full = (const float*)d_in[6];
  const float* embedding = (const float*)d_in[8];
  const float* W_ih = (const float*)d_in[9];
  const float* W_hh = (const float*)d_in[10];
  const float* b_ih = (const float*)d_in[11];
  const float* b_hh = (const float*)d_in[12];
  const float* W_init_h = (const float*)d_in[13];
  const float* b_init_h = (const float*)d_in[14];
  const float* W_init_c = (const float*)d_in[15];
  const float* b_init_c = (const float*)d_in[16];
  const float* W_f_beta = (const float*)d_in[17];
  const float* b_f_beta = (const float*)d_in[18];
  const float* W_fc = (const float*)d_in[19];
  const float* b_fc = (const float*)d_in[20];

  float* out = (float*)d_out;
  float* preds = out;                             // 64*20*9490 = 12,147,200
  float* alphas = out + (size_t)BB * TDEC * VOC;  // 64*20*196
  // Dead-before-fc aliases inside the preds region:
  float* att1 = preds;                                     // 6,422,528 f
  float* gates0 = preds + (size_t)BB * PP * ATTD;          // 2,621,440 f
  u16* WTh_h = (u16*)(gates0 + (size_t)TDEC * BB * 2048);  // 4608*512 u16
  u16* WTh_l = WTh_h + (size_t)4608 * DECD;                // ends @ 11,403,264 f

  float* ws = (float*)d_ws;
  float* c = ws;                        // 32768
  float* F2 = c + BB * DECD;            // 163840
  float* scores = F2 + BB * F2STR;      // 12544
  float* gates = scores + BB * PP;      // 131072
  float* mean = gates + BB * 4 * DECD;  // 131072
  float* awe = mean + BB * ENCD;        // 131072
  float* Hbuf = awe + BB * ENCD;        // 21*32768 = 688128
  u16* WTi_h = (u16*)(Hbuf + (size_t)(TDEC + 1) * BB * DECD);  // 2048*2048 u16
  u16* WTi_l = WTi_h + (size_t)2048 * ENCD;
  // Union region: {WTa + WTit} (pre-phase) then {WTf} (after att1/embgates)
  u16* U = WTi_l + (size_t)2048 * ENCD;
  u16* WTa_h = U;
  u16* WTa_l = WTa_h + (size_t)ATTD * ENCD;
  u16* WTit_h = WTa_l + (size_t)ATTD * ENCD;
  u16* WTit_l = WTit_h + (size_t)2048 * DECD;
  u16* WTf_h = U;
  u16* WTf_l = WTf_h + (size_t)NFC2 * DECD;
  // ws total = 1,290,496 f + 8,388,608 u16 + 9,830,400 u16  = 41.6 MB

  hipMemsetAsync(c, 0, (size_t)BB * DECD * 4, stream);
  hipMemsetAsync(Hbuf, 0, (size_t)BB * DECD * 4, stream);  // h0 accumulator

  // one-time weight transposes+splits (WTf deferred: shares U with WTa/WTit)
  convT_kernel<<<dim3(32, 8), 256, 0, stream>>>(W_enc_att, ATTD, ENCD, ATTD, WTa_h, WTa_l);
  convT_kernel<<<dim3(8, 8), 256, 0, stream>>>(W_dec_att, ATTD, DECD, ATTD, WTh_h, WTh_l);
  convT_kernel<<<dim3(8, 32), 256, 0, stream>>>(W_f_beta, ENCD, DECD, ENCD,
                                                WTh_h + (size_t)512 * DECD,
                                                WTh_l + (size_t)512 * DECD);
  convT_kernel<<<dim3(8, 32), 256, 0, stream>>>(W_hh, 2048, DECD, 2048,
                                                WTh_h + (size_t)2560 * DECD,
                                                WTh_l + (size_t)2560 * DECD);
  convT_kernel<<<dim3(8, 32), 256, 0, stream>>>(W_ih, 2048, DECD, 2048, WTit_h, WTit_l);
  convT_kernel<<<dim3(32, 32), 256, 0, stream>>>(W_ih + (size_t)512 * 2048, 2048, ENCD,
                                                 2048, WTi_h, WTi_l);

  mean_kernel<<<BB * ENCD / 4, 256, 0, stream>>>(enc, mean);
  gemm64_atomic<<<dim3(DECD / 64, 4), 256, 0, stream>>>(mean, ENCD, W_init_h, DECD,
                                                        Hbuf, DECD, b_init_h, 512);
  gemm64_atomic<<<dim3(DECD / 64, 4), 256, 0, stream>>>(mean, ENCD, W_init_c, DECD, c,
                                                        DECD, b_init_c, 512);
  embgates_mfma<<<dim3(16, TDEC), 256, 0, stream>>>(captions, embedding, WTit_h,
                                                    WTit_l, b_ih, b_hh, gates0);
  att1_mfma<<<dim3(2, 196), 256, 0, stream>>>(enc, WTa_h, WTa_l, b_enc_att, att1);
  // WTa/WTit now dead -> build WTf over the union region
  convT_kernel<<<dim3(8, NFC2 / 64), 256, 0, stream>>>(W_fc, VOC, DECD, VOC, WTf_h,
                                                       WTf_l);

  for (int t = 0; t < TDEC; ++t) {
    const float* hprev = Hbuf + (size_t)t * BB * DECD;
    float* hnext = Hbuf + (size_t)(t + 1) * BB * DECD;
    hgemm_mfma<<<36, 256, 0, stream>>>(hprev, WTh_h, WTh_l, b_dec_att, b_f_beta,
                                       gates0 + (size_t)t * BB * 2048, F2, gates);
    score_kernel<<<BB * PP / 4, 256, 0, stream>>>(att1, F2, W_full, scores);
    awe_softmax_kernel<<<dim3(ENCD / 256, BB), 256, 0, stream>>>(scores, F2, enc,
                                                                 alphas, awe, t);
    gates_mfma<<<dim3(16, 2), 256, 0, stream>>>(awe, WTi_h, WTi_l, gates);
    lstm_kernel<<<BB * DECD / 256, 256, 0, stream>>>(gates, c, hnext);
  }
  fc_mfma<<<dim3(NFC2 / 128, TDEC * BB / 64), 256, 0, stream>>>(Hbuf + BB * DECD,
                                                                WTf_h, WTf_l, b_fc,
                                                                preds);
}

// Round 4
// 2011.364 us; speedup vs baseline: 2.0827x; 2.0827x over previous
//
#include <hip/hip_runtime.h>
#include <cstddef>

#define BB 64
#define PP 196
#define ENCD 2048
#define DECD 512
#define ATTD 512
#define EMBD 512
#define VOC 9490
#define NFC 9536  // VOC padded to 64-col tiles
#define TDEC 20
#define F2STR 2560  // F2 row: [att2 512 | gate 2048]

using u16 = unsigned short;
using short8 = __attribute__((ext_vector_type(8))) short;   // 8 bf16 (4 VGPRs)
using f32x16 = __attribute__((ext_vector_type(16))) float;  // 32x32 acc

__device__ __forceinline__ float sigmoidf_(float x) { return 1.f / (1.f + __expf(-x)); }

// ---- fp32 -> bf16 RNE, and hi/lo split (x ~= hi + lo, err ~2^-17 |x|) -----
__device__ __forceinline__ unsigned rne_bf(float x) {
  unsigned u = __float_as_uint(x);
  return (u + 0x7FFFu + ((u >> 16) & 1u)) >> 16;
}
__device__ __forceinline__ void split_bf(float x, u16& h, u16& l) {
  unsigned hu = rne_bf(x);
  h = (u16)hu;
  float hf = __uint_as_float(hu << 16);
  l = (u16)rne_bf(x - hf);
}
__device__ __forceinline__ uint4 pack8(const u16* s) {
  uint4 r;
  r.x = (unsigned)s[0] | ((unsigned)s[1] << 16);
  r.y = (unsigned)s[2] | ((unsigned)s[3] << 16);
  r.z = (unsigned)s[4] | ((unsigned)s[5] << 16);
  r.w = (unsigned)s[6] | ((unsigned)s[7] << 16);
  return r;
}

// Swizzled elem offset into a 64x64 u16 LDS tile: row stride 128B = 8 x 16B
// blocks; block index XOR row&7 -> conflict-floor b128 write AND read.
#define LADDRE(row, bk) (((row) << 6) + ((((bk) ^ ((row)&7))) << 3))

#define MFMA_TRIPLE(ACC, AH, AL, BH, BL)                                      \
  ACC = __builtin_amdgcn_mfma_f32_32x32x16_bf16(AH, BH, ACC, 0, 0, 0);        \
  ACC = __builtin_amdgcn_mfma_f32_32x32x16_bf16(AH, BL, ACC, 0, 0, 0);        \
  ACC = __builtin_amdgcn_mfma_f32_32x32x16_bf16(AL, BH, ACC, 0, 0, 0);

// C/D layout (verified r1): col = lane&31, row = (g&3) + 8*(g>>2) + 4*(lane>>5)
#define OROW(wr, g, lh) ((wr)*32 + ((g)&3) + 8 * ((g) >> 2) + 4 * (lh))

// ---- one-time: W[k][n] (k<K, row-stride ld) fp32 -> Th/Tl [Npad64][K] ------
__global__ __launch_bounds__(256) void convT_kernel(const float* __restrict__ W,
                                                    int ld, int K, int N,
                                                    u16* __restrict__ Th,
                                                    u16* __restrict__ Tl) {
  __shared__ u16 ht[64][66], lt[64][66];
  int t = threadIdx.x;
  int k0 = blockIdx.x * 64, n0 = blockIdx.y * 64;
  int nl = t & 63, kq = t >> 6;
  int n = n0 + nl;
#pragma unroll
  for (int i = 0; i < 16; ++i) {
    int k = kq * 16 + i;
    float v = (n < N) ? W[(size_t)(k0 + k) * ld + n] : 0.f;
    u16 h, l;
    split_bf(v, h, l);
    ht[k][nl] = h;
    lt[k][nl] = l;
  }
  __syncthreads();
  int n2 = t >> 2, q = t & 3;
  u16 h16[16], l16[16];
#pragma unroll
  for (int i = 0; i < 16; ++i) {
    h16[i] = ht[q * 16 + i][n2];
    l16[i] = lt[q * 16 + i][n2];
  }
  size_t ob = (size_t)(n0 + n2) * K + k0 + q * 16;
  *(uint4*)(Th + ob) = pack8(h16);
  *(uint4*)(Th + ob + 8) = pack8(h16 + 8);
  *(uint4*)(Tl + ob) = pack8(l16);
  *(uint4*)(Tl + ob + 8) = pack8(l16 + 8);
}

// ---- proven 64x64 split-bf16 MFMA core (round-1 structure, VGPR ~48) ------
// a_s: this thread's A ptr (row t&63, k-ofs (t>>6)*16), contiguous in k.
// bh_s/bl_s: this thread's B ptr (row n0+(t>>2), k-ofs (t&3)*16).
// 4 waves in 2x2 grid; wave (wr,wc) computes one 32x32 tile; single acc.
__device__ __forceinline__ void core64(const float* a_s, const u16* bh_s,
                                       const u16* bl_s, int k0s, int k0e,
                                       u16* Ah, u16* Al, u16* Bh, u16* Bl,
                                       f32x16& acc) {
  int t = threadIdx.x;
  int ar = t & 63, akc = t >> 6;
  int bn = t >> 2, bq = t & 3;
  int l31 = t & 31, lh = (t >> 5) & 1;
  int wr = (t >> 7) & 1, wc = (t >> 6) & 1;
  for (int k0 = k0s; k0 < k0e; k0 += 64) {
    float av[16];
    *(float4*)(av + 0) = *(const float4*)(a_s + k0);
    *(float4*)(av + 4) = *(const float4*)(a_s + k0 + 4);
    *(float4*)(av + 8) = *(const float4*)(a_s + k0 + 8);
    *(float4*)(av + 12) = *(const float4*)(a_s + k0 + 12);
    uint4 b0 = *(const uint4*)(bh_s + k0);
    uint4 b1 = *(const uint4*)(bh_s + k0 + 8);
    uint4 b2 = *(const uint4*)(bl_s + k0);
    uint4 b3 = *(const uint4*)(bl_s + k0 + 8);
    u16 h[16], l[16];
#pragma unroll
    for (int i = 0; i < 16; ++i) split_bf(av[i], h[i], l[i]);
    __syncthreads();  // previous iteration's fragment reads done
    *(uint4*)(Ah + LADDRE(ar, akc * 2)) = pack8(h);
    *(uint4*)(Ah + LADDRE(ar, akc * 2 + 1)) = pack8(h + 8);
    *(uint4*)(Al + LADDRE(ar, akc * 2)) = pack8(l);
    *(uint4*)(Al + LADDRE(ar, akc * 2 + 1)) = pack8(l + 8);
    *(uint4*)(Bh + LADDRE(bn, bq * 2)) = b0;
    *(uint4*)(Bh + LADDRE(bn, bq * 2 + 1)) = b1;
    *(uint4*)(Bl + LADDRE(bn, bq * 2)) = b2;
    *(uint4*)(Bl + LADDRE(bn, bq * 2 + 1)) = b3;
    __syncthreads();
#pragma unroll
    for (int ks = 0; ks < 4; ++ks) {
      int bk = ks * 2 + lh;
      short8 a_h = *(const short8*)(Ah + LADDRE(wr * 32 + l31, bk));
      short8 a_l = *(const short8*)(Al + LADDRE(wr * 32 + l31, bk));
      short8 b_h = *(const short8*)(Bh + LADDRE(wc * 32 + l31, bk));
      short8 b_l = *(const short8*)(Bl + LADDRE(wc * 32 + l31, bk));
      MFMA_TRIPLE(acc, a_h, a_l, b_h, b_l);
    }
  }
}

// ---- att1 = enc(b,k,p)^T @ W_enc_att + bias (round-1 proven, 153 us) ------
__global__ __launch_bounds__(256) void att1_mfma(const float* __restrict__ enc,
                                                 const u16* __restrict__ BTh,
                                                 const u16* __restrict__ BTl,
                                                 const float* __restrict__ bea,
                                                 float* __restrict__ att1) {
  __shared__ u16 Ah[64 * 64], Al[64 * 64], Bh[64 * 64], Bl[64 * 64];
  int t = threadIdx.x;
  int a0 = blockIdx.x * 64;       // grid.x = 8
  int rowbase = blockIdx.y * 64;  // grid.y = 196
  int ar = t & 63, akc = t >> 6;
  int r = rowbase + ar;
  int ab = r / PP;
  int ap = r - ab * PP;
  const float* asrc = enc + (size_t)ab * (ENCD * PP) + ap;
  int bn = t >> 2, bq = t & 3;
  const u16* bsh = BTh + (size_t)(a0 + bn) * ENCD + bq * 16;
  const u16* bsl = BTl + (size_t)(a0 + bn) * ENCD + bq * 16;
  int lane = t & 63;
  int wr = (t >> 7) & 1, wc = (t >> 6) & 1;
  int l31 = lane & 31, lh = lane >> 5;
  f32x16 acc;
#pragma unroll
  for (int i = 0; i < 16; ++i) acc[i] = 0.f;

  for (int k0 = 0; k0 < ENCD; k0 += 64) {
    float av[16];
#pragma unroll
    for (int i = 0; i < 16; ++i) av[i] = asrc[(size_t)(k0 + akc * 16 + i) * PP];
    u16 h[16], l[16];
#pragma unroll
    for (int i = 0; i < 16; ++i) split_bf(av[i], h[i], l[i]);
    uint4 b0 = *(const uint4*)(bsh + k0);
    uint4 b1 = *(const uint4*)(bsh + k0 + 8);
    uint4 b2 = *(const uint4*)(bsl + k0);
    uint4 b3 = *(const uint4*)(bsl + k0 + 8);
    __syncthreads();  // previous iteration's fragment reads done
    *(uint4*)(Ah + LADDRE(ar, akc * 2)) = pack8(h);
    *(uint4*)(Ah + LADDRE(ar, akc * 2 + 1)) = pack8(h + 8);
    *(uint4*)(Al + LADDRE(ar, akc * 2)) = pack8(l);
    *(uint4*)(Al + LADDRE(ar, akc * 2 + 1)) = pack8(l + 8);
    *(uint4*)(Bh + LADDRE(bn, bq * 2)) = b0;
    *(uint4*)(Bh + LADDRE(bn, bq * 2 + 1)) = b1;
    *(uint4*)(Bl + LADDRE(bn, bq * 2)) = b2;
    *(uint4*)(Bl + LADDRE(bn, bq * 2 + 1)) = b3;
    __syncthreads();
#pragma unroll
    for (int ks = 0; ks < 4; ++ks) {
      int bk = ks * 2 + lh;
      short8 a_h = *(const short8*)(Ah + LADDRE(wr * 32 + l31, bk));
      short8 a_l = *(const short8*)(Al + LADDRE(wr * 32 + l31, bk));
      short8 b_h = *(const short8*)(Bh + LADDRE(wc * 32 + l31, bk));
      short8 b_l = *(const short8*)(Bl + LADDRE(wc * 32 + l31, bk));
      MFMA_TRIPLE(acc, a_h, a_l, b_h, b_l);
    }
  }
  int col = a0 + wc * 32 + l31;
  float bv = bea[col];
#pragma unroll
  for (int g = 0; g < 16; ++g) {
    int row = rowbase + OROW(wr, g, lh);
    att1[(size_t)row * ATTD + col] = acc[g] + bv;
  }
}

// ---- gates0[t*64+b][n] = emb(tok) @ W_ih_top + b_ih + b_hh (fused gather) --
__global__ __launch_bounds__(256) void embgates_mfma(
    const int* __restrict__ captions, const float* __restrict__ embedding,
    const u16* __restrict__ Bh_g, const u16* __restrict__ Bl_g,
    const float* __restrict__ b1, const float* __restrict__ b2,
    float* __restrict__ gates0) {
  __shared__ u16 Ah[4096], Al[4096], Bh[4096], Bl[4096];
  int t = threadIdx.x;
  int n0 = blockIdx.x * 64;  // grid (32, 20)
  int tt = blockIdx.y;
  int tok = captions[(t & 63) * 21 + tt];
  const float* a_s = embedding + (size_t)tok * EMBD + (t >> 6) * 16;
  const u16* bh_s = Bh_g + (size_t)(n0 + (t >> 2)) * DECD + (t & 3) * 16;
  const u16* bl_s = Bl_g + (size_t)(n0 + (t >> 2)) * DECD + (t & 3) * 16;
  f32x16 acc;
#pragma unroll
  for (int i = 0; i < 16; ++i) acc[i] = 0.f;
  core64(a_s, bh_s, bl_s, 0, DECD, Ah, Al, Bh, Bl, acc);
  int l31 = t & 31, lh = (t >> 5) & 1;
  int wr = (t >> 7) & 1, wc = (t >> 6) & 1;
  int col = n0 + wc * 32 + l31;
  float bv = b1[col] + b2[col];
#pragma unroll
  for (int g = 0; g < 16; ++g) {
    int row = tt * 64 + OROW(wr, g, lh);
    gates0[(size_t)row * 2048 + col] = acc[g] + bv;
  }
}

// ---- per-step: h @ [Wdec | Wfbeta(sigmoid) | Whh(+gates0)], 64-col tiles ---
__global__ __launch_bounds__(256) void hgemm_mfma(
    const float* __restrict__ hprev, const u16* __restrict__ Bh_g,
    const u16* __restrict__ Bl_g, const float* __restrict__ bdec,
    const float* __restrict__ bfb, const float* __restrict__ g0,
    float* __restrict__ F2, float* __restrict__ gates) {
  __shared__ u16 Ah[4096], Al[4096], Bh[4096], Bl[4096];
  int t = threadIdx.x;
  int n0 = blockIdx.x * 64;  // grid 72
  const float* a_s = hprev + (size_t)(t & 63) * DECD + (t >> 6) * 16;
  const u16* bh_s = Bh_g + (size_t)(n0 + (t >> 2)) * DECD + (t & 3) * 16;
  const u16* bl_s = Bl_g + (size_t)(n0 + (t >> 2)) * DECD + (t & 3) * 16;
  f32x16 acc;
#pragma unroll
  for (int i = 0; i < 16; ++i) acc[i] = 0.f;
  core64(a_s, bh_s, bl_s, 0, DECD, Ah, Al, Bh, Bl, acc);
  int l31 = t & 31, lh = (t >> 5) & 1;
  int wr = (t >> 7) & 1, wc = (t >> 6) & 1;
  int col = n0 + wc * 32 + l31;
#pragma unroll
  for (int g = 0; g < 16; ++g) {
    int b = OROW(wr, g, lh);
    float v = acc[g];
    if (n0 < ATTD) {
      F2[(size_t)b * F2STR + col] = v + bdec[col];
    } else if (n0 < ATTD + ENCD) {
      F2[(size_t)b * F2STR + col] = sigmoidf_(v + bfb[col - ATTD]);
    } else {
      int cg = col - (ATTD + ENCD);
      gates[(size_t)b * 2048 + cg] = v + g0[(size_t)b * 2048 + cg];
    }
  }
}

// ---- per-step: gates += awe @ W_ih_bot (K=2048, 4-way k-split atomic) ------
__global__ __launch_bounds__(256) void gates_mfma(const float* __restrict__ awe,
                                                  const u16* __restrict__ Bh_g,
                                                  const u16* __restrict__ Bl_g,
                                                  float* __restrict__ gates) {
  __shared__ u16 Ah[4096], Al[4096], Bh[4096], Bl[4096];
  int t = threadIdx.x;
  int n0 = blockIdx.x * 64;  // grid (32, 4)
  int k0s = blockIdx.y * 512;
  const float* a_s = awe + (size_t)(t & 63) * ENCD + (t >> 6) * 16;
  const u16* bh_s = Bh_g + (size_t)(n0 + (t >> 2)) * ENCD + (t & 3) * 16;
  const u16* bl_s = Bl_g + (size_t)(n0 + (t >> 2)) * ENCD + (t & 3) * 16;
  f32x16 acc;
#pragma unroll
  for (int i = 0; i < 16; ++i) acc[i] = 0.f;
  core64(a_s, bh_s, bl_s, k0s, k0s + 512, Ah, Al, Bh, Bl, acc);
  int l31 = t & 31, lh = (t >> 5) & 1;
  int wr = (t >> 7) & 1, wc = (t >> 6) & 1;
  int col = n0 + wc * 32 + l31;
#pragma unroll
  for (int g = 0; g < 16; ++g) {
    int b = OROW(wr, g, lh);
    atomicAdd(&gates[(size_t)b * 2048 + col], acc[g]);
  }
}

// ---- preds = Hfc(1280x512) @ W_fc + b_fc (round-1 proven shape) -----------
__global__ __launch_bounds__(256) void fc_mfma(const float* __restrict__ Hfc,
                                               const u16* __restrict__ Bh_g,
                                               const u16* __restrict__ Bl_g,
                                               const float* __restrict__ bfc,
                                               float* __restrict__ preds) {
  __shared__ u16 Ah[4096], Al[4096], Bh[4096], Bl[4096];
  int t = threadIdx.x;
  int n0 = blockIdx.x * 64;  // grid (149, 20)
  int rowbase = blockIdx.y * 64;
  const float* a_s = Hfc + (size_t)(rowbase + (t & 63)) * DECD + (t >> 6) * 16;
  const u16* bh_s = Bh_g + (size_t)(n0 + (t >> 2)) * DECD + (t & 3) * 16;
  const u16* bl_s = Bl_g + (size_t)(n0 + (t >> 2)) * DECD + (t & 3) * 16;
  f32x16 acc;
#pragma unroll
  for (int i = 0; i < 16; ++i) acc[i] = 0.f;
  core64(a_s, bh_s, bl_s, 0, DECD, Ah, Al, Bh, Bl, acc);
  int l31 = t & 31, lh = (t >> 5) & 1;
  int wr = (t >> 7) & 1, wc = (t >> 6) & 1;
  int col = n0 + wc * 32 + l31;
  if (col < VOC) {
    float bv = bfc[col];
#pragma unroll
    for (int g = 0; g < 16; ++g) {
      int rr = rowbase + OROW(wr, g, lh);
      preds[(size_t)(rr & 63) * (TDEC * VOC) + (size_t)(rr >> 6) * VOC + col] =
          acc[g] + bv;
    }
  }
}

// ---------------- mean over P of encoder_out rows (B*ENC rows of 196) -------
__global__ __launch_bounds__(256) void mean_kernel(const float* __restrict__ enc,
                                                   float* __restrict__ mean) {
  int row = blockIdx.x * 4 + (threadIdx.x >> 6);
  int lane = threadIdx.x & 63;
  const float* r = enc + (size_t)row * PP;
  float v = r[lane] + r[lane + 64] + r[lane + 128];
  if (lane < 4) v += r[lane + 192];
#pragma unroll
  for (int off = 32; off; off >>= 1) v += __shfl_down(v, off);
  if (lane == 0) mean[row] = v * (1.f / 196.f);
}

// ---------------- 64-row x 64-col GEMM, k-split atomic (init h0/c0) ---------
__global__ __launch_bounds__(256) void gemm64_atomic(
    const float* __restrict__ A, int lda, const float* __restrict__ W, int ldw,
    float* __restrict__ C, int ldc, const float* __restrict__ bias0, int kchunk) {
  __shared__ __align__(16) float As[16][68];
  int tid = threadIdx.x;
  int my = tid >> 4, nx = tid & 15;
  int am = tid >> 2, ak = (tid & 3) << 2;
  int n0 = blockIdx.x * 64;
  int k0s = blockIdx.y * kchunk, k0e = k0s + kchunk;
  float acc[4][4] = {};
  for (int k0 = k0s; k0 < k0e; k0 += 16) {
    float4 a4 = *(const float4*)(A + (size_t)am * lda + k0 + ak);
    As[ak + 0][am] = a4.x;
    As[ak + 1][am] = a4.y;
    As[ak + 2][am] = a4.z;
    As[ak + 3][am] = a4.w;
    __syncthreads();
    const float* wp = W + (size_t)k0 * ldw + n0 + (nx << 2);
#pragma unroll
    for (int kk = 0; kk < 16; ++kk) {
      float4 av = *(const float4*)&As[kk][my << 2];
      float4 wv = *(const float4*)(wp + (size_t)kk * ldw);
      acc[0][0] = fmaf(av.x, wv.x, acc[0][0]); acc[0][1] = fmaf(av.x, wv.y, acc[0][1]);
      acc[0][2] = fmaf(av.x, wv.z, acc[0][2]); acc[0][3] = fmaf(av.x, wv.w, acc[0][3]);
      acc[1][0] = fmaf(av.y, wv.x, acc[1][0]); acc[1][1] = fmaf(av.y, wv.y, acc[1][1]);
      acc[1][2] = fmaf(av.y, wv.z, acc[1][2]); acc[1][3] = fmaf(av.y, wv.w, acc[1][3]);
      acc[2][0] = fmaf(av.z, wv.x, acc[2][0]); acc[2][1] = fmaf(av.z, wv.y, acc[2][1]);
      acc[2][2] = fmaf(av.z, wv.z, acc[2][2]); acc[2][3] = fmaf(av.z, wv.w, acc[2][3]);
      acc[3][0] = fmaf(av.w, wv.x, acc[3][0]); acc[3][1] = fmaf(av.w, wv.y, acc[3][1]);
      acc[3][2] = fmaf(av.w, wv.z, acc[3][2]); acc[3][3] = fmaf(av.w, wv.w, acc[3][3]);
    }
    __syncthreads();
  }
  bool first = (blockIdx.y == 0);
#pragma unroll
  for (int i = 0; i < 4; ++i) {
    int row = (my << 2) + i;
#pragma unroll
    for (int j = 0; j < 4; ++j) {
      int col = n0 + (nx << 2) + j;
      float v = acc[i][j];
      if (first && bias0) v += bias0[col];
      atomicAdd(&C[(size_t)row * ldc + col], v);
    }
  }
}

// -------- score[b,p] = sum_a relu(att1+att2)*wf : one wave per (b,p) --------
__global__ __launch_bounds__(256) void score_kernel(const float* __restrict__ att1,
                                                    const float* __restrict__ F2,
                                                    const float* __restrict__ W_full,
                                                    float* __restrict__ scores) {
  int w = blockIdx.x * 4 + (threadIdx.x >> 6);  // [0, 12544)
  int lane = threadIdx.x & 63;
  int b = w / PP, p = w - b * PP;
  const float4* row = (const float4*)(att1 + ((size_t)b * PP + p) * ATTD) + (lane << 1);
  const float4* a2 = (const float4*)(F2 + (size_t)b * F2STR) + (lane << 1);
  const float4* w4 = (const float4*)W_full + (lane << 1);
  float acc = 0.f;
#pragma unroll
  for (int i = 0; i < 2; ++i) {
    float4 v = row[i], a = a2[i], wf = w4[i];
    acc = fmaf(fmaxf(v.x + a.x, 0.f), wf.x, acc);
    acc = fmaf(fmaxf(v.y + a.y, 0.f), wf.y, acc);
    acc = fmaf(fmaxf(v.z + a.z, 0.f), wf.z, acc);
    acc = fmaf(fmaxf(v.w + a.w, 0.f), wf.w, acc);
  }
#pragma unroll
  for (int off = 32; off; off >>= 1) acc += __shfl_down(acc, off);
  if (lane == 0) scores[b * PP + p] = acc;
}

// -------- softmax(196) per block + gated awe for a 256-wide e-slice ---------
__global__ __launch_bounds__(256) void awe_softmax_kernel(
    const float* __restrict__ scores, const float* __restrict__ F2,
    const float* __restrict__ enc, float* __restrict__ alphas_out,
    float* __restrict__ awe, int t) {
  int b = blockIdx.y, et = blockIdx.x, tid = threadIdx.x;
  __shared__ __align__(16) float al[256];
  __shared__ float sc[256];
  __shared__ float red[256];
  float s = (tid < PP) ? scores[b * PP + tid] : -1e30f;
  sc[tid] = s;
  __syncthreads();
  for (int off = 128; off; off >>= 1) {
    if (tid < off) sc[tid] = fmaxf(sc[tid], sc[tid + off]);
    __syncthreads();
  }
  float e = (tid < PP) ? __expf(s - sc[0]) : 0.f;
  red[tid] = e;
  __syncthreads();
  for (int off = 128; off; off >>= 1) {
    if (tid < off) red[tid] += red[tid + off];
    __syncthreads();
  }
  float a = e * (1.f / red[0]);
  al[tid] = a;
  if (et == 0 && tid < PP)
    alphas_out[(size_t)b * (TDEC * PP) + (size_t)t * PP + tid] = a;
  __syncthreads();
  int e0 = et * 256 + tid;
  const float4* row = (const float4*)(enc + ((size_t)b * ENCD + e0) * PP);
  const float4* al4 = (const float4*)al;
  float acc = 0.f;
#pragma unroll 7
  for (int i = 0; i < PP / 4; ++i) {
    float4 v = row[i], aa = al4[i];
    acc = fmaf(v.x, aa.x, acc);
    acc = fmaf(v.y, aa.y, acc);
    acc = fmaf(v.z, aa.z, acc);
    acc = fmaf(v.w, aa.w, acc);
  }
  float gate = F2[(size_t)b * F2STR + ATTD + e0];
  awe[(size_t)b * ENCD + e0] = gate * acc;
}

// ---- LSTM pointwise -> h into Hbuf slot ------------------------------------
__global__ __launch_bounds__(256) void lstm_kernel(const float* __restrict__ gates,
                                                   float* __restrict__ c,
                                                   float* __restrict__ hout) {
  int idx = blockIdx.x * 256 + threadIdx.x;  // 0..32767
  int b = idx >> 9, d = idx & 511;
  const float* g = gates + (size_t)b * 2048;
  float gi = g[d], gf = g[d + 512], gg = g[d + 1024], go = g[d + 1536];
  float iv = sigmoidf_(gi);
  float fv = sigmoidf_(gf);
  float ov = sigmoidf_(go);
  float gv = tanhf(gg);
  float cn = fv * c[idx] + iv * gv;
  c[idx] = cn;
  hout[idx] = ov * tanhf(cn);
}

extern "C" void kernel_launch(void* const* d_in, const int* in_sizes, int n_in,
                              void* d_out, int out_size, void* d_ws, size_t ws_size,
                              hipStream_t stream) {
  const float* enc = (const float*)d_in[0];
  const int* captions = (const int*)d_in[1];
  const float* W_enc_att = (const float*)d_in[2];
  const float* b_enc_att = (const float*)d_in[3];
  const float* W_dec_att = (const float*)d_in[4];
  const float* b_dec_att = (const float*)d_in[5];
  const float* W_full = (const float*)d_in[6];
  const float* embedding = (const float*)d_in[8];
  const float* W_ih = (const float*)d_in[9];
  const float* W_hh = (const float*)d_in[10];
  const float* b_ih = (const float*)d_in[11];
  const float* b_hh = (const float*)d_in[12];
  const float* W_init_h = (const float*)d_in[13];
  const float* b_init_h = (const float*)d_in[14];
  const float* W_init_c = (const float*)d_in[15];
  const float* b_init_c = (const float*)d_in[16];
  const float* W_f_beta = (const float*)d_in[17];
  const float* b_f_beta = (const float*)d_in[18];
  const float* W_fc = (const float*)d_in[19];
  const float* b_fc = (const float*)d_in[20];

  float* out = (float*)d_out;
  float* preds = out;                             // 64*20*9490 = 12,147,200 f
  float* alphas = out + (size_t)BB * TDEC * VOC;  // 64*20*196
  // Dead-before-fc aliases inside the preds region:
  float* att1 = preds;                                     // 6,422,528 f
  float* gates0 = preds + (size_t)BB * PP * ATTD;          // 2,621,440 f
  u16* WTh_h = (u16*)(gates0 + (size_t)TDEC * BB * 2048);  // 4608*512 u16
  u16* WTh_l = WTh_h + (size_t)4608 * DECD;                // ends @ 11,403,264 f

  float* ws = (float*)d_ws;
  float* c = ws;                        // 32768
  float* F2 = c + BB * DECD;            // 163840
  float* scores = F2 + BB * F2STR;      // 12544
  float* gates = scores + BB * PP;      // 131072
  float* mean = gates + BB * 4 * DECD;  // 131072
  float* awe = mean + BB * ENCD;        // 131072
  float* Hbuf = awe + BB * ENCD;        // 21*32768 = 688128
  u16* WTi_h = (u16*)(Hbuf + (size_t)(TDEC + 1) * BB * DECD);  // 2048*2048 u16
  u16* WTi_l = WTi_h + (size_t)2048 * ENCD;
  // Union region: {WTa + WTit} (pre-phase) then {WTf} (after att1/embgates)
  u16* U = WTi_l + (size_t)2048 * ENCD;
  u16* WTa_h = U;
  u16* WTa_l = WTa_h + (size_t)ATTD * ENCD;
  u16* WTit_h = WTa_l + (size_t)ATTD * ENCD;
  u16* WTit_l = WTit_h + (size_t)2048 * DECD;
  u16* WTf_h = U;
  u16* WTf_l = WTf_h + (size_t)NFC * DECD;
  // ws total ~41.5 MB (passed in r3)

  hipMemsetAsync(c, 0, (size_t)BB * DECD * 4, stream);
  hipMemsetAsync(Hbuf, 0, (size_t)BB * DECD * 4, stream);  // h0 accumulator

  // one-time weight transposes+splits (WTf deferred: shares U with WTa/WTit)
  convT_kernel<<<dim3(32, 8), 256, 0, stream>>>(W_enc_att, ATTD, ENCD, ATTD, WTa_h, WTa_l);
  convT_kernel<<<dim3(8, 8), 256, 0, stream>>>(W_dec_att, ATTD, DECD, ATTD, WTh_h, WTh_l);
  convT_kernel<<<dim3(8, 32), 256, 0, stream>>>(W_f_beta, ENCD, DECD, ENCD,
                                                WTh_h + (size_t)512 * DECD,
                                                WTh_l + (size_t)512 * DECD);
  convT_kernel<<<dim3(8, 32), 256, 0, stream>>>(W_hh, 2048, DECD, 2048,
                                                WTh_h + (size_t)2560 * DECD,
                                                WTh_l + (size_t)2560 * DECD);
  convT_kernel<<<dim3(8, 32), 256, 0, stream>>>(W_ih, 2048, DECD, 2048, WTit_h, WTit_l);
  convT_kernel<<<dim3(32, 32), 256, 0, stream>>>(W_ih + (size_t)512 * 2048, 2048, ENCD,
                                                 2048, WTi_h, WTi_l);

  mean_kernel<<<BB * ENCD / 4, 256, 0, stream>>>(enc, mean);
  gemm64_atomic<<<dim3(DECD / 64, 4), 256, 0, stream>>>(mean, ENCD, W_init_h, DECD,
                                                        Hbuf, DECD, b_init_h, 512);
  gemm64_atomic<<<dim3(DECD / 64, 4), 256, 0, stream>>>(mean, ENCD, W_init_c, DECD, c,
                                                        DECD, b_init_c, 512);
  embgates_mfma<<<dim3(32, TDEC), 256, 0, stream>>>(captions, embedding, WTit_h,
                                                    WTit_l, b_ih, b_hh, gates0);
  att1_mfma<<<dim3(8, 196), 256, 0, stream>>>(enc, WTa_h, WTa_l, b_enc_att, att1);
  // WTa/WTit now dead -> build WTf over the union region
  convT_kernel<<<dim3(8, NFC / 64), 256, 0, stream>>>(W_fc, VOC, DECD, VOC, WTf_h,
                                                      WTf_l);

  for (int t = 0; t < TDEC; ++t) {
    const float* hprev = Hbuf + (size_t)t * BB * DECD;
    float* hnext = Hbuf + (size_t)(t + 1) * BB * DECD;
    hgemm_mfma<<<72, 256, 0, stream>>>(hprev, WTh_h, WTh_l, b_dec_att, b_f_beta,
                                       gates0 + (size_t)t * BB * 2048, F2, gates);
    score_kernel<<<BB * PP / 4, 256, 0, stream>>>(att1, F2, W_full, scores);
    awe_softmax_kernel<<<dim3(ENCD / 256, BB), 256, 0, stream>>>(scores, F2, enc,
                                                                 alphas, awe, t);
    gates_mfma<<<dim3(32, 4), 256, 0, stream>>>(awe, WTi_h, WTi_l, gates);
    lstm_kernel<<<BB * DECD / 256, 256, 0, stream>>>(gates, c, hnext);
  }
  fc_mfma<<<dim3(NFC / 64, TDEC * BB / 64), 256, 0, stream>>>(Hbuf + BB * DECD,
                                                              WTf_h, WTf_l, b_fc,
                                                              preds);
}